// Round 5
// baseline (567.972 us; speedup 1.0000x reference)
//
#include <hip/hip_runtime.h>
#include <cstdint>
#include <cstddef>

#define NB    32          // batches
#define SEQ   1024        // sequence length
#define DIN   256
#define HID   512
#define MTOT  32768       // NB*SEQ

typedef _Float16 half_t;
typedef _Float16 half8  __attribute__((ext_vector_type(8)));
typedef _Float16 half4v __attribute__((ext_vector_type(4)));
typedef float    f32x4  __attribute__((ext_vector_type(4)));

typedef __attribute__((address_space(1))) const void* gas_ptr;
typedef __attribute__((address_space(3))) void*       las_ptr;

// raw-barrier / counted-wait primitives (T3/T4): loads stay in flight across barriers
#define VMWAIT(n) asm volatile("s_waitcnt vmcnt(" #n ")" ::: "memory")
#define LGWAIT0() asm volatile("s_waitcnt lgkmcnt(0)" ::: "memory")
#define SBAR()    __builtin_amdgcn_s_barrier()
#define SCHED0()  __builtin_amdgcn_sched_barrier(0)
#define CFENCE()  asm volatile("" ::: "memory")

// ---------------- f32 -> f16 convert ----------------
__global__ void cvt_kernel(const float* __restrict__ src, half_t* __restrict__ dst, int n4) {
    int i = blockIdx.x * blockDim.x + threadIdx.x;
    if (i < n4) {
        f32x4 v = ((const f32x4*)src)[i];
        half4v h;
        h[0] = (half_t)v[0]; h[1] = (half_t)v[1]; h[2] = (half_t)v[2]; h[3] = (half_t)v[3];
        ((half4v*)dst)[i] = h;
    }
}

__global__ void cvt4_kernel(const float* __restrict__ s0, const float* __restrict__ s1,
                            const float* __restrict__ s2, const float* __restrict__ s3,
                            half_t* __restrict__ d0, half_t* __restrict__ d1,
                            half_t* __restrict__ d2, half_t* __restrict__ d3, int n4) {
    int y = blockIdx.y;
    const float* s = y == 0 ? s0 : y == 1 ? s1 : y == 2 ? s2 : s3;
    half_t*      d = y == 0 ? d0 : y == 1 ? d1 : y == 2 ? d2 : d3;
    int i = blockIdx.x * blockDim.x + threadIdx.x;
    if (i < n4) {
        f32x4 v = ((const f32x4*)s)[i];
        half4v h;
        h[0] = (half_t)v[0]; h[1] = (half_t)v[1]; h[2] = (half_t)v[2]; h[3] = (half_t)v[3];
        ((half4v*)d)[i] = h;
    }
}

__global__ void pack_bias(const float* __restrict__ bv, const float* __restrict__ bk,
                          const float* __restrict__ bq, float* __restrict__ dst) {
    int t = threadIdx.x;
    if (t < HID) {
        dst[t]         = bv[t];
        dst[HID + t]   = bk[t];
        dst[2*HID + t] = bq[t];
    }
}

// ---------------- generic GEMM (projections), 128x128 tile ----------------
template<int MODE>
__global__ __launch_bounds__(256, 2) void gemm_k(
    const half_t* __restrict__ A, long lda, long a_bs,
    const half_t* __restrict__ Bw, long ldb, long b_bs,
    void* __restrict__ Out, long ldo, long o_bs,
    const float* __restrict__ bias,
    int Kdim, half_t* __restrict__ out2)
{
    __shared__ alignas(16) half_t As[128 * 32];
    __shared__ alignas(16) half_t Bs[128 * 32];

    const int t    = threadIdx.x;
    const int lane = t & 63;
    const int wave = t >> 6;
    const int wm   = wave >> 1;
    const int wn   = wave & 1;
    const int lanen = lane & 15;
    const int quad  = lane >> 4;
    const int z     = blockIdx.z;
    const long m0 = (long)blockIdx.x * 128;
    const long n0 = (long)blockIdx.y * 128;

    const half_t* Ab = A  + (long)z * a_bs;
    const half_t* Bb = Bw + (long)z * b_bs;

    f32x4 acc[4][4];
#pragma unroll
    for (int i = 0; i < 4; i++)
#pragma unroll
        for (int j = 0; j < 4; j++)
            acc[i][j] = f32x4{0.f, 0.f, 0.f, 0.f};

    const int c0 = t, c1 = t + 256;
    const int r0 = c0 >> 2, kc0 = c0 & 3;
    const int r1 = c1 >> 2, kc1 = c1 & 3;

    const half_t* gA0 = Ab + (m0 + r0) * lda + kc0 * 8;
    const half_t* gA1 = Ab + (m0 + r1) * lda + kc1 * 8;
    const half_t* gB0 = Bb + (n0 + r0) * ldb + kc0 * 8;
    const half_t* gB1 = Bb + (n0 + r1) * ldb + kc1 * 8;
    half_t* lA0 = &As[c0 * 8];
    half_t* lA1 = &As[c1 * 8];
    half_t* lB0 = &Bs[c0 * 8];
    half_t* lB1 = &Bs[c1 * 8];

    int aoff[4], boff[4];
#pragma unroll
    for (int i = 0; i < 4; i++) aoff[i] = (wm * 64 + i * 16 + lanen) * 32 + quad * 8;
#pragma unroll
    for (int j = 0; j < 4; j++) boff[j] = (wn * 64 + j * 16 + lanen) * 32 + quad * 8;

    for (int k0 = 0; k0 < Kdim; k0 += 32) {
        __builtin_amdgcn_global_load_lds((gas_ptr)(gA0 + k0), (las_ptr)lA0, 16, 0, 0);
        __builtin_amdgcn_global_load_lds((gas_ptr)(gA1 + k0), (las_ptr)lA1, 16, 0, 0);
        __builtin_amdgcn_global_load_lds((gas_ptr)(gB0 + k0), (las_ptr)lB0, 16, 0, 0);
        __builtin_amdgcn_global_load_lds((gas_ptr)(gB1 + k0), (las_ptr)lB1, 16, 0, 0);
        __syncthreads();

        half8 af[4], bf[4];
#pragma unroll
        for (int i = 0; i < 4; i++) af[i] = *(const half8*)&As[aoff[i]];
#pragma unroll
        for (int j = 0; j < 4; j++) bf[j] = *(const half8*)&Bs[boff[j]];
#pragma unroll
        for (int i = 0; i < 4; i++)
#pragma unroll
            for (int j = 0; j < 4; j++)
                acc[i][j] = __builtin_amdgcn_mfma_f32_16x16x32_f16(af[i], bf[j], acc[i][j], 0, 0, 0);
        __syncthreads();
    }

#pragma unroll
    for (int i = 0; i < 4; i++) {
        long mrow = m0 + wm * 64 + i * 16 + quad * 4;
#pragma unroll
        for (int j = 0; j < 4; j++) {
            long gn = n0 + wn * 64 + j * 16 + lanen;
            f32x4 v = acc[i][j];
            if (MODE == 0) {
                float bb = bias[z * HID + gn];
                half_t h0 = (half_t)fmaxf(v[0] + bb, 0.f);
                half_t h1 = (half_t)fmaxf(v[1] + bb, 0.f);
                half_t h2 = (half_t)fmaxf(v[2] + bb, 0.f);
                half_t h3 = (half_t)fmaxf(v[3] + bb, 0.f);
                if (z == 0) {
                    long bidx = mrow >> 10;
                    long pos  = mrow & 1023;
                    half4v pk; pk[0] = h0; pk[1] = h1; pk[2] = h2; pk[3] = h3;
                    *(half4v*)(out2 + ((bidx * HID + gn) << 10) + pos) = pk;
                } else {
                    half_t* o = (half_t*)Out + (long)(z - 1) * o_bs;
                    o[(mrow + 0) * ldo + gn] = h0;
                    o[(mrow + 1) * ldo + gn] = h1;
                    o[(mrow + 2) * ldo + gn] = h2;
                    o[(mrow + 3) * ldo + gn] = h3;
                }
            } else {
                float* o = (float*)Out;
                float bb = bias[gn];
#pragma unroll
                for (int r = 0; r < 4; r++) o[(mrow + r) * ldo + gn] = fmaxf(v[r] + bb, 0.f);
            }
        }
    }
}

// ---------------- fused flash attention (64-q-row blocks, register-fitting) ----------------
// One block = 64 Q rows. 8 waves. S phase: wave w owns S cols [w*16,w*16+16) (acc 16 f32).
// PV phase: wave w owns h cols [w*64,w*64+64) (acc2 64 f32). Total regs ~160 <= 256.
// hid-chunk 64: staging = 3 loads/thread uniform (1 Q + 2 K); V chunk [512h][32kv] = 4 loads.
// All LDS frag reads conflict-free via slot XOR swizzles (pre-swizzled global source).
// Counted vmcnt: S chunks wait(3) (7th: 4); PV wait(4) (last: 3 / drain at end).
// Q and O alias (in-place) -> no __restrict__ on them.

#define STAGE_S(dst, kv0_, ho_)                                                        \
    do {                                                                               \
        __builtin_amdgcn_global_load_lds((gas_ptr)(Qb + qoff + (ho_)),                 \
                                         (las_ptr)((dst) + t * 8), 16, 0, 0);          \
        _Pragma("unroll")                                                              \
        for (int s2_ = 0; s2_ < 2; s2_++) {                                            \
            int s_ = t + 512 * s2_;                                                    \
            __builtin_amdgcn_global_load_lds(                                          \
                (gas_ptr)(Kb + (long)(kv0_) * HID + koff[s2_] + (ho_)),                \
                (las_ptr)((dst) + 4096 + s_ * 8), 16, 0, 0);                           \
        }                                                                              \
    } while (0)

#define STAGE_V(dst, kv0_, kc_)                                                        \
    do {                                                                               \
        _Pragma("unroll")                                                              \
        for (int s2_ = 0; s2_ < 4; s2_++) {                                            \
            int s_ = t + 512 * s2_;                                                    \
            __builtin_amdgcn_global_load_lds(                                          \
                (gas_ptr)(Vb + voff[s2_] + (kv0_) + (kc_) * 32),                       \
                (las_ptr)((dst) + s_ * 8), 16, 0, 0);                                  \
        }                                                                              \
    } while (0)

__global__ __launch_bounds__(512) __attribute__((amdgpu_waves_per_eu(2, 2)))
void flash_k(const half_t* Q, const half_t* __restrict__ K,
             const half_t* __restrict__ vT, half_t* O)
{
    // LDS map (87040 B):
    //  [0,64K):    union: sb0=[0,24K) sb1=[32K,56K) (Q 8K + K 16K each)
    //              vb0=[0,32K) vb1=[32K,64K)        (vT chunk 512x32)
    //              safety: vb0∩sb1=∅ (V0 staged while sb1 live), sb0∩vb1=∅ (S0' while vb1 live)
    //  [64K,80K):  Ps 64x128 f16 (slot-swizzled, 256B rows)
    //  [80K,..):   m_s,l_s,al_s,mn_s (64 f32 each), pm[64][8], psum[64][8]
    __shared__ alignas(16) unsigned char SM[87040];
    half_t* Uh   = (half_t*)SM;
    half_t* Ps   = (half_t*)(SM + 65536);
    float*  m_s  = (float*)(SM + 81920);
    float*  l_s  = (float*)(SM + 82176);
    float*  al_s = (float*)(SM + 82432);
    float*  mn_s = (float*)(SM + 82688);
    float*  pm   = (float*)(SM + 82944);   // 64*8 f32
    float*  psum = (float*)(SM + 84992);   // 64*8 f32

    half_t* const sb0 = Uh;                // 24KB
    half_t* const sb1 = Uh + 16384;        // 24KB at byte 32768
    half_t* const vb0 = Uh;                // 32KB
    half_t* const vb1 = Uh + 16384;        // 32KB at byte 32768

    const int t     = threadIdx.x;
    const int lane  = t & 63;
    const int wv    = t >> 6;       // 0..7
    const int lanen = lane & 15;
    const int quad  = lane >> 4;
    const int sl7   = lanen & 7;

    // XCD swizzle: batch z's 16 m-blocks land on XCD (z&7)
    const int bid = blockIdx.x;
    const int z   = (bid & 7) + 8 * ((bid >> 3) & 3);
    const long m0 = (long)(bid >> 5) * 64;

    const half_t* Qb = Q  + (long)z * SEQ * HID + m0 * HID;
    const half_t* Kb = K  + (long)z * SEQ * HID;
    const half_t* Vb = vT + (long)z * HID * SEQ;
    half_t*       Ob = O  + (long)z * SEQ * HID + m0 * HID;

    // per-thread staging source offsets (half units), inverse-swizzled so linear
    // LDS dest + swizzled read = conflict-free (T2 both-sides rule)
    const long qoff = (long)(t >> 3) * HID + (long)(((t & 7) ^ ((t >> 3) & 7)) * 8);
    long koff[2], voff[4];
#pragma unroll
    for (int s2 = 0; s2 < 2; s2++) {
        int s = t + 512 * s2;
        koff[s2] = (long)(s >> 3) * HID + (long)(((s & 7) ^ ((s >> 3) & 7)) * 8);
    }
#pragma unroll
    for (int s2 = 0; s2 < 4; s2++) {
        int s = t + 512 * s2;
        voff[s2] = (long)(s >> 2) * SEQ + (long)((((s & 3) ^ ((s >> 3) & 3)) * 8));
    }

    const int vslot16 = (quad ^ ((lanen >> 1) & 3)) * 16;  // V read slot byte offset

    if (t < 64) { m_s[t] = -1e30f; l_s[t] = 0.f; }

    // O^T accumulators: acc2[a][b]: h = wv*64+a*16+quad*4+rr, q = b*16+lanen
    f32x4 acc2[4][4];
#pragma unroll
    for (int a = 0; a < 4; a++)
#pragma unroll
        for (int b = 0; b < 4; b++) acc2[a][b] = f32x4{0.f,0.f,0.f,0.f};

    // prologue: S chunks 0,1 of tile 0 in flight (3 loads each)
    STAGE_S(sb0, 0, 0);
    STAGE_S(sb1, 0, 64);

    for (int kt = 0; kt < 8; kt++) {
        const int kv0 = kt * 128;

        // ---- S phase: 8 hid-chunks of 64 ----
        f32x4 acc[4];
#pragma unroll
        for (int i = 0; i < 4; i++) acc[i] = f32x4{0.f,0.f,0.f,0.f};

        for (int c = 0; c < 8; c++) {
            if (c == 7) VMWAIT(4); else VMWAIT(3);   // buf-c landed; next batch in flight
            SBAR();
            SCHED0();
            const char* Qc = (const char*)((c & 1) ? sb1 : sb0);
            const char* Kc = Qc + 8192;
            // K frag: rows wv*16+lanen (this wave's 16 S-cols), 2 k-steps
            const int krow = (wv * 16 + lanen) * 128;
            half8 bf0 = *(const half8*)(Kc + krow + ((quad ^ sl7) * 16));
            half8 bf1 = *(const half8*)(Kc + krow + (((quad + 4) ^ sl7) * 16));
            half8 af0[4], af1[4];
#pragma unroll
            for (int i = 0; i < 4; i++) {
                const int arow = (i * 16 + lanen) * 128;
                af0[i] = *(const half8*)(Qc + arow + ((quad ^ sl7) * 16));
                af1[i] = *(const half8*)(Qc + arow + (((quad + 4) ^ sl7) * 16));
            }
            LGWAIT0();
            SCHED0();
            SBAR();                        // all waves done reading buf c
            CFENCE();
            if (c <= 5)       STAGE_S((c & 1) ? sb1 : sb0, kv0, (c + 2) * 64);
            else if (c == 6)  STAGE_V(vb0, kv0, 0);        // V0 rides the softmax phase
            else              STAGE_V(vb1, kv0, 1);
            SCHED0();
            __builtin_amdgcn_s_setprio(1);
#pragma unroll
            for (int i = 0; i < 4; i++) {
                acc[i] = __builtin_amdgcn_mfma_f32_16x16x32_f16(af0[i], bf0, acc[i], 0, 0, 0);
                acc[i] = __builtin_amdgcn_mfma_f32_16x16x32_f16(af1[i], bf1, acc[i], 0, 0, 0);
            }
            __builtin_amdgcn_s_setprio(0);
        }

        // ---- softmax: partial max (16 cols) -> pm -> merge -> exp -> Ps + psum ----
#pragma unroll
        for (int i = 0; i < 4; i++) {
#pragma unroll
            for (int rr = 0; rr < 4; rr++) {
                float v = acc[i][rr];
                v = fmaxf(v, __shfl_xor(v, 1, 64));
                v = fmaxf(v, __shfl_xor(v, 2, 64));
                v = fmaxf(v, __shfl_xor(v, 4, 64));
                v = fmaxf(v, __shfl_xor(v, 8, 64));
                if (lanen == 0) pm[(i * 16 + quad * 4 + rr) * 8 + wv] = v;
            }
        }
        LGWAIT0();
        SBAR();                            // pm visible (V loads stay in flight)

#pragma unroll
        for (int i = 0; i < 4; i++) {
#pragma unroll
            for (int rr = 0; rr < 4; rr++) {
                const int row = i * 16 + quad * 4 + rr;
                f32x4 p4a = *(const f32x4*)&pm[row * 8];
                f32x4 p4b = *(const f32x4*)&pm[row * 8 + 4];
                float tm = fmaxf(fmaxf(fmaxf(p4a[0], p4a[1]), fmaxf(p4a[2], p4a[3])),
                                 fmaxf(fmaxf(p4b[0], p4b[1]), fmaxf(p4b[2], p4b[3])));
                float mo = m_s[row];
                float mn = fmaxf(mo, tm);
                float e  = __expf(acc[i][rr] - mn);
                // Ps[row][col], slot-swizzled: byte = row*256 + ((col*2) ^ ((row&7)<<4))
                const int colb = (wv * 16 + lanen) * 2;
                *(half_t*)((char*)Ps + row * 256 + (colb ^ ((row & 7) << 4))) = (half_t)e;
                float s = e;
                s += __shfl_xor(s, 1, 64);
                s += __shfl_xor(s, 2, 64);
                s += __shfl_xor(s, 4, 64);
                s += __shfl_xor(s, 8, 64);
                if (lanen == 0) {
                    psum[row * 8 + wv] = s;
                    if (wv == 0) { al_s[row] = __expf(mo - mn); mn_s[row] = mn; }
                }
            }
        }
        LGWAIT0();
        SBAR();                            // Ps + psum + al_s/mn_s visible

        // finalize running stats (wave 0, lanen==0); readers are beyond later barriers
        if (wv == 0 && lanen == 0) {
#pragma unroll
            for (int i = 0; i < 4; i++)
#pragma unroll
                for (int rr = 0; rr < 4; rr++) {
                    const int row = i * 16 + quad * 4 + rr;
                    f32x4 s4a = *(const f32x4*)&psum[row * 8];
                    f32x4 s4b = *(const f32x4*)&psum[row * 8 + 4];
                    l_s[row] = l_s[row] * al_s[row] +
                               (s4a[0] + s4a[1] + s4a[2] + s4a[3] +
                                s4b[0] + s4b[1] + s4b[2] + s4b[3]);
                    m_s[row] = mn_s[row];
                }
        }

        // rescale O accumulator by alpha (per q column)
#pragma unroll
        for (int b = 0; b < 4; b++) {
            float al = al_s[b * 16 + lanen];
#pragma unroll
            for (int a = 0; a < 4; a++) {
                acc2[a][b][0] *= al; acc2[a][b][1] *= al;
                acc2[a][b][2] *= al; acc2[a][b][3] *= al;
            }
        }

        // ---- PV phase: 4 kv-subchunks of 32; O^T = V^T P^T ----
        for (int kc = 0; kc < 4; kc++) {
            if (kc == 3) { if (kt < 7) VMWAIT(3); else VMWAIT(0); }
            else VMWAIT(4);
            SBAR();
            SCHED0();
            const char* Vc = (const char*)((kc & 1) ? vb1 : vb0);
            half8 pf[4], vf[4];
#pragma unroll
            for (int b = 0; b < 4; b++)
                pf[b] = *(const half8*)((const char*)Ps + (b * 16 + lanen) * 256 +
                                        (((kc * 4 + quad) ^ sl7) * 16));
#pragma unroll
            for (int a = 0; a < 4; a++)
                vf[a] = *(const half8*)(Vc + (wv * 64 + a * 16 + lanen) * 64 + vslot16);
            LGWAIT0();
            SCHED0();
            SBAR();                        // all waves done reading vb[kc] / Ps needs persist anyway
            CFENCE();
            if (kc == 0)      STAGE_V(vb0, kv0, 2);
            else if (kc == 1) STAGE_V(vb1, kv0, 3);
            else if (kc == 2) { if (kt < 7) STAGE_S(sb0, kv0 + 128, 0); }
            else              { if (kt < 7) STAGE_S(sb1, kv0 + 128, 64); }
            SCHED0();
            __builtin_amdgcn_s_setprio(1);
#pragma unroll
            for (int a = 0; a < 4; a++)
#pragma unroll
                for (int b = 0; b < 4; b++)
                    acc2[a][b] = __builtin_amdgcn_mfma_f32_16x16x32_f16(vf[a], pf[b], acc2[a][b], 0, 0, 0);
            __builtin_amdgcn_s_setprio(0);
        }
    }

    // ---- epilogue: normalize, f16, store (8B per store: 4 consecutive h) ----
    // (kt=7 kc=3 did VMWAIT(0): all Q/K/V loads retired; O aliases Q safely)
#pragma unroll
    for (int b = 0; b < 4; b++) {
        long qg = b * 16 + lanen;
        float inv = 1.f / l_s[qg];
#pragma unroll
        for (int a = 0; a < 4; a++) {
            f32x4 v = acc2[a][b];
            half4v pk;
            pk[0] = (half_t)(v[0] * inv); pk[1] = (half_t)(v[1] * inv);
            pk[2] = (half_t)(v[2] * inv); pk[3] = (half_t)(v[3] * inv);
            *(half4v*)&Ob[qg * HID + wv * 64 + a * 16 + quad * 4] = pk;
        }
    }
}

// ---------------- host ----------------
extern "C" void kernel_launch(void* const* d_in, const int* in_sizes, int n_in,
                              void* d_out, int out_size, void* d_ws, size_t ws_size,
                              hipStream_t stream) {
    const float* h  = (const float*)d_in[0];
    const float* Wv = (const float*)d_in[1];
    const float* bv = (const float*)d_in[2];
    const float* Wk = (const float*)d_in[3];
    const float* bk = (const float*)d_in[4];
    const float* Wq = (const float*)d_in[5];
    const float* bq = (const float*)d_in[6];
    const float* Wo = (const float*)d_in[7];
    const float* bo = (const float*)d_in[8];

    uint8_t* ws = (uint8_t*)d_ws;
    size_t off = 0;
    auto alloc = [&](size_t bytes) { size_t o = off; off += (bytes + 255) & ~(size_t)255; return o; };

    half_t* W16   = (half_t*)(ws + alloc((size_t)3 * HID * DIN * 2)); // [Wv][Wk][Wq]
    half_t* Wo16  = (half_t*)(ws + alloc((size_t)DIN * HID * 2));
    float*  biasq = (float*)(ws + alloc((size_t)3 * HID * 4));        // [bv][bk][bq]
    half_t* k16   = (half_t*)(ws + alloc((size_t)MTOT * HID * 2));
    half_t* q16   = (half_t*)(ws + alloc((size_t)MTOT * HID * 2));    // Q; overwritten in-place by O
    half_t* vT    = (half_t*)(ws + alloc((size_t)MTOT * HID * 2));    // [b][h][m]
    half_t* h16   = (half_t*)(ws + alloc((size_t)MTOT * DIN * 2));

    // K0: conversions
    cvt_kernel<<<dim3((MTOT * DIN / 4 + 255) / 256), 256, 0, stream>>>(h, h16, MTOT * DIN / 4);
    cvt4_kernel<<<dim3((HID * DIN / 4 + 255) / 256, 4), 256, 0, stream>>>(
        Wv, Wk, Wq, Wo, W16, W16 + HID * DIN, W16 + 2 * HID * DIN, Wo16, HID * DIN / 4);
    pack_bias<<<dim3(1), 512, 0, stream>>>(bv, bk, bq, biasq);

    // K1: QKV projections (z: 0=V->vT, 1=K, 2=Q)
    gemm_k<0><<<dim3(MTOT / 128, HID / 128, 3), 256, 0, stream>>>(
        h16, DIN, 0,
        W16, DIN, (long)HID * DIN,
        (void*)k16, HID, (long)MTOT * HID,
        biasq, DIN, vT);

    // K2: fused flash attention, 64-row blocks (writes O in place of Q)
    flash_k<<<dim3(NB * (SEQ / 64)), dim3(512), 0, stream>>>(q16, k16, vT, q16);

    // K3: out = relu(O Wo^T + bo)  (f32 out)
    gemm_k<3><<<dim3(MTOT / 128, DIN / 128, 1), 256, 0, stream>>>(
        q16, HID, 0,
        Wo16, HID, 0,
        d_out, DIN, 0,
        bo, HID, nullptr);

    (void)in_sizes; (void)n_in; (void)out_size; (void)ws_size;
}

// Round 6
// 279.743 us; speedup vs baseline: 2.0303x; 2.0303x over previous
//
#include <hip/hip_runtime.h>
#include <cstdint>
#include <cstddef>

#define NB    32          // batches
#define SEQ   1024        // sequence length
#define DIN   256
#define HID   512
#define MTOT  32768       // NB*SEQ

typedef _Float16 half_t;
typedef _Float16 half8  __attribute__((ext_vector_type(8)));
typedef _Float16 half4v __attribute__((ext_vector_type(4)));
typedef float    f32x4  __attribute__((ext_vector_type(4)));

typedef __attribute__((address_space(1))) const void* gas_ptr;
typedef __attribute__((address_space(3))) void*       las_ptr;

// ---------------- f32 -> f16 convert ----------------
__global__ void cvt_kernel(const float* __restrict__ src, half_t* __restrict__ dst, int n4) {
    int i = blockIdx.x * blockDim.x + threadIdx.x;
    if (i < n4) {
        f32x4 v = ((const f32x4*)src)[i];
        half4v h;
        h[0] = (half_t)v[0]; h[1] = (half_t)v[1]; h[2] = (half_t)v[2]; h[3] = (half_t)v[3];
        ((half4v*)dst)[i] = h;
    }
}

// all 4 weight matrices are HID*DIN == DIN*HID elements; blockIdx.y selects
__global__ void cvt4_kernel(const float* __restrict__ s0, const float* __restrict__ s1,
                            const float* __restrict__ s2, const float* __restrict__ s3,
                            half_t* __restrict__ d0, half_t* __restrict__ d1,
                            half_t* __restrict__ d2, half_t* __restrict__ d3, int n4) {
    int y = blockIdx.y;
    const float* s = y == 0 ? s0 : y == 1 ? s1 : y == 2 ? s2 : s3;
    half_t*      d = y == 0 ? d0 : y == 1 ? d1 : y == 2 ? d2 : d3;
    int i = blockIdx.x * blockDim.x + threadIdx.x;
    if (i < n4) {
        f32x4 v = ((const f32x4*)s)[i];
        half4v h;
        h[0] = (half_t)v[0]; h[1] = (half_t)v[1]; h[2] = (half_t)v[2]; h[3] = (half_t)v[3];
        ((half4v*)d)[i] = h;
    }
}

__global__ void pack_bias(const float* __restrict__ bv, const float* __restrict__ bk,
                          const float* __restrict__ bq, float* __restrict__ dst) {
    int t = threadIdx.x;
    if (t < HID) {
        dst[t]         = bv[t];
        dst[HID + t]   = bk[t];
        dst[2*HID + t] = bq[t];
    }
}

// ---------------- generic GEMM (projections), 128x128 tile ----------------
// C[m][n] = sum_k A[m][k] * B[n][k]
// K-loop unrolled x2: two 32-wide sub-buffers, ONE sync per 64-wide step
// (halves barrier/drain count vs round-0 baseline; per-sub LDS pattern identical).
// MODE 0: QKV proj. bias+relu, f16 out. z=0 -> transposed into out2 (vT[b][h][m]); z=1,2 -> row-major.
// MODE 3: out proj. f32 out, bias+relu.
template<int MODE>
__global__ __launch_bounds__(256, 2) void gemm_k(
    const half_t* __restrict__ A, long lda, long a_bs,
    const half_t* __restrict__ Bw, long ldb, long b_bs,
    void* __restrict__ Out, long ldo, long o_bs,
    const float* __restrict__ bias,
    int Kdim, half_t* __restrict__ out2)
{
    __shared__ alignas(16) half_t As[2][128 * 32];
    __shared__ alignas(16) half_t Bs[2][128 * 32];

    const int t    = threadIdx.x;
    const int lane = t & 63;
    const int wave = t >> 6;
    const int wm   = wave >> 1;
    const int wn   = wave & 1;
    const int lanen = lane & 15;
    const int quad  = lane >> 4;
    const int z     = blockIdx.z;
    const long m0 = (long)blockIdx.x * 128;
    const long n0 = (long)blockIdx.y * 128;

    const half_t* Ab = A  + (long)z * a_bs;
    const half_t* Bb = Bw + (long)z * b_bs;

    f32x4 acc[4][4];
#pragma unroll
    for (int i = 0; i < 4; i++)
#pragma unroll
        for (int j = 0; j < 4; j++)
            acc[i][j] = f32x4{0.f, 0.f, 0.f, 0.f};

    const int c0 = t, c1 = t + 256;
    const int r0 = c0 >> 2, kc0 = c0 & 3;
    const int r1 = c1 >> 2, kc1 = c1 & 3;

    const half_t* gA0 = Ab + (m0 + r0) * lda + kc0 * 8;
    const half_t* gA1 = Ab + (m0 + r1) * lda + kc1 * 8;
    const half_t* gB0 = Bb + (n0 + r0) * ldb + kc0 * 8;
    const half_t* gB1 = Bb + (n0 + r1) * ldb + kc1 * 8;
    const int lA0 = c0 * 8, lA1 = c1 * 8;
    const int lB0 = c0 * 8, lB1 = c1 * 8;

    int aoff[4], boff[4];
#pragma unroll
    for (int i = 0; i < 4; i++) aoff[i] = (wm * 64 + i * 16 + lanen) * 32 + quad * 8;
#pragma unroll
    for (int j = 0; j < 4; j++) boff[j] = (wn * 64 + j * 16 + lanen) * 32 + quad * 8;

    for (int k0 = 0; k0 < Kdim; k0 += 64) {
#pragma unroll
        for (int sub = 0; sub < 2; sub++) {
            const int ks = k0 + sub * 32;
            __builtin_amdgcn_global_load_lds((gas_ptr)(gA0 + ks), (las_ptr)&As[sub][lA0], 16, 0, 0);
            __builtin_amdgcn_global_load_lds((gas_ptr)(gA1 + ks), (las_ptr)&As[sub][lA1], 16, 0, 0);
            __builtin_amdgcn_global_load_lds((gas_ptr)(gB0 + ks), (las_ptr)&Bs[sub][lB0], 16, 0, 0);
            __builtin_amdgcn_global_load_lds((gas_ptr)(gB1 + ks), (las_ptr)&Bs[sub][lB1], 16, 0, 0);
        }
        __syncthreads();

        {
            half8 af[4], bf[4];
#pragma unroll
            for (int i = 0; i < 4; i++) af[i] = *(const half8*)&As[0][aoff[i]];
#pragma unroll
            for (int j = 0; j < 4; j++) bf[j] = *(const half8*)&Bs[0][boff[j]];
#pragma unroll
            for (int i = 0; i < 4; i++)
#pragma unroll
                for (int j = 0; j < 4; j++)
                    acc[i][j] = __builtin_amdgcn_mfma_f32_16x16x32_f16(af[i], bf[j], acc[i][j], 0, 0, 0);
        }
        {
            half8 af[4], bf[4];
#pragma unroll
            for (int i = 0; i < 4; i++) af[i] = *(const half8*)&As[1][aoff[i]];
#pragma unroll
            for (int j = 0; j < 4; j++) bf[j] = *(const half8*)&Bs[1][boff[j]];
#pragma unroll
            for (int i = 0; i < 4; i++)
#pragma unroll
                for (int j = 0; j < 4; j++)
                    acc[i][j] = __builtin_amdgcn_mfma_f32_16x16x32_f16(af[i], bf[j], acc[i][j], 0, 0, 0);
        }
        __syncthreads();
    }

    // C/D layout: col = lane&15, row = quad*4 + reg
#pragma unroll
    for (int i = 0; i < 4; i++) {
        long mrow = m0 + wm * 64 + i * 16 + quad * 4;
#pragma unroll
        for (int j = 0; j < 4; j++) {
            long gn = n0 + wn * 64 + j * 16 + lanen;
            f32x4 v = acc[i][j];
            if (MODE == 0) {
                float bb = bias[z * HID + gn];
                half_t h0 = (half_t)fmaxf(v[0] + bb, 0.f);
                half_t h1 = (half_t)fmaxf(v[1] + bb, 0.f);
                half_t h2 = (half_t)fmaxf(v[2] + bb, 0.f);
                half_t h3 = (half_t)fmaxf(v[3] + bb, 0.f);
                if (z == 0) {
                    long bidx = mrow >> 10;
                    long pos  = mrow & 1023;
                    half4v pk; pk[0] = h0; pk[1] = h1; pk[2] = h2; pk[3] = h3;
                    *(half4v*)(out2 + ((bidx * HID + gn) << 10) + pos) = pk;
                } else {
                    half_t* o = (half_t*)Out + (long)(z - 1) * o_bs;
                    o[(mrow + 0) * ldo + gn] = h0;
                    o[(mrow + 1) * ldo + gn] = h1;
                    o[(mrow + 2) * ldo + gn] = h2;
                    o[(mrow + 3) * ldo + gn] = h3;
                }
            } else {
                float* o = (float*)Out;
                float bb = bias[gn];
#pragma unroll
                for (int r = 0; r < 4; r++) o[(mrow + r) * ldo + gn] = fmaxf(v[r] + bb, 0.f);
            }
        }
    }
}

// ---------------- S = q k^T with fused exp, 128x256 tile ----------------
// K-loop unrolled x2 (two 32-wide sub-buffers, one sync pair per 64-wide step).
// Each wave-column (wn) spans exactly one 128-col stats block -> per-wave stats.
// Writes E = exp(s - m_loc) f16 + Mstat/Lstat per (row, kb).
__global__ __launch_bounds__(256, 2) void se_k(
    const half_t* __restrict__ Q, const half_t* __restrict__ K,
    half_t* __restrict__ E, float* __restrict__ Mstat, float* __restrict__ Lstat)
{
    __shared__ alignas(16) half_t As[2][128 * 32];
    __shared__ alignas(16) half_t Bs[2][256 * 32];

    const int t    = threadIdx.x;
    const int lane = t & 63;
    const int wave = t >> 6;
    const int wm   = wave >> 1;
    const int wn   = wave & 1;
    const int lanen = lane & 15;
    const int quad  = lane >> 4;
    const int z     = blockIdx.z;
    const long m0 = (long)blockIdx.x * 128;
    const long n0 = (long)blockIdx.y * 256;

    const half_t* Ab = Q + (long)z * SEQ * HID;
    const half_t* Bb = K + (long)z * SEQ * HID;

    f32x4 acc[4][8];
#pragma unroll
    for (int i = 0; i < 4; i++)
#pragma unroll
        for (int j = 0; j < 8; j++)
            acc[i][j] = f32x4{0.f, 0.f, 0.f, 0.f};

    // A: 512 chunks (2/thread), B: 1024 chunks (4/thread); chunk c -> row c>>2, kchunk c&3
    const half_t* gA[2]; int lA[2];
    const half_t* gB[4]; int lB[4];
#pragma unroll
    for (int s = 0; s < 2; s++) {
        int c = t + 256 * s;
        gA[s] = Ab + (m0 + (c >> 2)) * HID + (c & 3) * 8;
        lA[s] = c * 8;
    }
#pragma unroll
    for (int s = 0; s < 4; s++) {
        int c = t + 256 * s;
        gB[s] = Bb + (n0 + (c >> 2)) * HID + (c & 3) * 8;
        lB[s] = c * 8;
    }

    int aoff[4], boff[8];
#pragma unroll
    for (int i = 0; i < 4; i++) aoff[i] = (wm * 64 + i * 16 + lanen) * 32 + quad * 8;
#pragma unroll
    for (int j = 0; j < 8; j++) boff[j] = (wn * 128 + j * 16 + lanen) * 32 + quad * 8;

    for (int k0 = 0; k0 < HID; k0 += 64) {
#pragma unroll
        for (int sub = 0; sub < 2; sub++) {
            const int ks = k0 + sub * 32;
#pragma unroll
            for (int s = 0; s < 2; s++)
                __builtin_amdgcn_global_load_lds((gas_ptr)(gA[s] + ks), (las_ptr)&As[sub][lA[s]], 16, 0, 0);
#pragma unroll
            for (int s = 0; s < 4; s++)
                __builtin_amdgcn_global_load_lds((gas_ptr)(gB[s] + ks), (las_ptr)&Bs[sub][lB[s]], 16, 0, 0);
        }
        __syncthreads();

        {
            half8 af[4], bf[8];
#pragma unroll
            for (int i = 0; i < 4; i++) af[i] = *(const half8*)&As[0][aoff[i]];
#pragma unroll
            for (int j = 0; j < 8; j++) bf[j] = *(const half8*)&Bs[0][boff[j]];
#pragma unroll
            for (int i = 0; i < 4; i++)
#pragma unroll
                for (int j = 0; j < 8; j++)
                    acc[i][j] = __builtin_amdgcn_mfma_f32_16x16x32_f16(af[i], bf[j], acc[i][j], 0, 0, 0);
        }
        {
            half8 af[4], bf[8];
#pragma unroll
            for (int i = 0; i < 4; i++) af[i] = *(const half8*)&As[1][aoff[i]];
#pragma unroll
            for (int j = 0; j < 8; j++) bf[j] = *(const half8*)&Bs[1][boff[j]];
#pragma unroll
            for (int i = 0; i < 4; i++)
#pragma unroll
                for (int j = 0; j < 8; j++)
                    acc[i][j] = __builtin_amdgcn_mfma_f32_16x16x32_f16(af[i], bf[j], acc[i][j], 0, 0, 0);
        }
        __syncthreads();
    }

    // ---- epilogue: per-wave row max over this wave's 128 cols ----
    float mf[4][4];
#pragma unroll
    for (int i = 0; i < 4; i++)
#pragma unroll
        for (int r = 0; r < 4; r++) {
            float v = acc[i][0][r];
#pragma unroll
            for (int j = 1; j < 8; j++) v = fmaxf(v, acc[i][j][r]);
#pragma unroll
            for (int off = 8; off > 0; off >>= 1)
                v = fmaxf(v, __shfl_xor(v, off, 64));
            mf[i][r] = v;
        }

    // ---- exp + row partial sums + E store ----
    half_t* Eb = E + (long)z * SEQ * SEQ;
    float rs[4][4];
#pragma unroll
    for (int i = 0; i < 4; i++)
#pragma unroll
        for (int r = 0; r < 4; r++) rs[i][r] = 0.f;
#pragma unroll
    for (int i = 0; i < 4; i++) {
        long mrow = m0 + wm * 64 + i * 16 + quad * 4;
#pragma unroll
        for (int j = 0; j < 8; j++) {
            long gn = n0 + wn * 128 + j * 16 + lanen;
#pragma unroll
            for (int r = 0; r < 4; r++) {
                float e = __expf(acc[i][j][r] - mf[i][r]);
                rs[i][r] += e;
                Eb[(mrow + r) * SEQ + gn] = (half_t)e;
            }
        }
    }
#pragma unroll
    for (int i = 0; i < 4; i++)
#pragma unroll
        for (int r = 0; r < 4; r++) {
            float v = rs[i][r];
#pragma unroll
            for (int off = 8; off > 0; off >>= 1)
                v += __shfl_xor(v, off, 64);
            rs[i][r] = v;
        }

    // stats: kb = blockIdx.y*2 + wn; rows are wave-private -> no conflicts
    if (lanen == 0) {
        long base = ((long)z * 8 + blockIdx.y * 2 + wn) * SEQ + m0 + wm * 64;
#pragma unroll
        for (int i = 0; i < 4; i++)
#pragma unroll
            for (int r = 0; r < 4; r++) {
                Mstat[base + i * 16 + quad * 4 + r] = mf[i][r];
                Lstat[base + i * 16 + quad * 4 + r] = rs[i][r];
            }
    }
}

// ---------------- O = P vT with stat-merge rescale + normalize, 128x256 tile ----------------
// K-loop unrolled x2 (two 32-wide sub-buffers, one sync pair per 64-wide step).
__global__ __launch_bounds__(256, 2) void pv_k(
    const half_t* __restrict__ E, const half_t* __restrict__ vT,
    const float* __restrict__ Mstat, const float* __restrict__ Lstat,
    half_t* __restrict__ O16)
{
    __shared__ alignas(16) half_t As[2][128 * 32];
    __shared__ alignas(16) half_t Bs[2][256 * 32];
    __shared__ float scaleS[8][128];
    __shared__ float invS[128];

    const int t    = threadIdx.x;
    const int lane = t & 63;
    const int wave = t >> 6;
    const int wm   = wave >> 1;
    const int wn   = wave & 1;
    const int lanen = lane & 15;
    const int quad  = lane >> 4;
    const int z     = blockIdx.z;
    const long m0 = (long)blockIdx.x * 128;
    const long h0 = (long)blockIdx.y * 256;

    // prologue: merge per-col-block stats for this block's 128 rows
    if (t < 128) {
        float mv[8];
        float M = -1e30f;
#pragma unroll
        for (int kb = 0; kb < 8; kb++) {
            mv[kb] = Mstat[((long)z * 8 + kb) * SEQ + m0 + t];
            M = fmaxf(M, mv[kb]);
        }
        float ls = 0.f;
#pragma unroll
        for (int kb = 0; kb < 8; kb++) {
            float sc = __expf(mv[kb] - M);
            scaleS[kb][t] = sc;
            ls += Lstat[((long)z * 8 + kb) * SEQ + m0 + t] * sc;
        }
        invS[t] = 1.f / ls;
    }
    __syncthreads();

    const half_t* Ab = E  + (long)z * SEQ * SEQ;
    const half_t* Bb = vT + (long)z * HID * SEQ;

    f32x4 acc[4][8];
#pragma unroll
    for (int i = 0; i < 4; i++)
#pragma unroll
        for (int j = 0; j < 8; j++)
            acc[i][j] = f32x4{0.f, 0.f, 0.f, 0.f};

    const half_t* gA[2]; int lA[2];
    const half_t* gB[4]; int lB[4];
#pragma unroll
    for (int s = 0; s < 2; s++) {
        int c = t + 256 * s;
        gA[s] = Ab + (m0 + (c >> 2)) * SEQ + (c & 3) * 8;
        lA[s] = c * 8;
    }
#pragma unroll
    for (int s = 0; s < 4; s++) {
        int c = t + 256 * s;
        gB[s] = Bb + (h0 + (c >> 2)) * SEQ + (c & 3) * 8;
        lB[s] = c * 8;
    }

    int aoff[4], boff[8];
#pragma unroll
    for (int i = 0; i < 4; i++) aoff[i] = (wm * 64 + i * 16 + lanen) * 32 + quad * 8;
#pragma unroll
    for (int j = 0; j < 8; j++) boff[j] = (wn * 128 + j * 16 + lanen) * 32 + quad * 8;

    for (int k0 = 0; k0 < SEQ; k0 += 64) {
#pragma unroll
        for (int sub = 0; sub < 2; sub++) {
            const int ks = k0 + sub * 32;
#pragma unroll
            for (int s = 0; s < 2; s++)
                __builtin_amdgcn_global_load_lds((gas_ptr)(gA[s] + ks), (las_ptr)&As[sub][lA[s]], 16, 0, 0);
#pragma unroll
            for (int s = 0; s < 4; s++)
                __builtin_amdgcn_global_load_lds((gas_ptr)(gB[s] + ks), (las_ptr)&Bs[sub][lB[s]], 16, 0, 0);
        }
        __syncthreads();

        const int kb = k0 >> 7;   // both 32-wide subs lie in the same 128-col stats block
        {
            half8 af[4], bf[8];
#pragma unroll
            for (int i = 0; i < 4; i++) {
                af[i] = *(const half8*)&As[0][aoff[i]];
                half_t sh = (half_t)scaleS[kb][wm * 64 + i * 16 + lanen];
                af[i] *= sh;   // per-row rescale exp(m_kb - M); A-operand row = lane&15
            }
#pragma unroll
            for (int j = 0; j < 8; j++) bf[j] = *(const half8*)&Bs[0][boff[j]];
#pragma unroll
            for (int i = 0; i < 4; i++)
#pragma unroll
                for (int j = 0; j < 8; j++)
                    acc[i][j] = __builtin_amdgcn_mfma_f32_16x16x32_f16(af[i], bf[j], acc[i][j], 0, 0, 0);
        }
        {
            half8 af[4], bf[8];
#pragma unroll
            for (int i = 0; i < 4; i++) {
                af[i] = *(const half8*)&As[1][aoff[i]];
                half_t sh = (half_t)scaleS[kb][wm * 64 + i * 16 + lanen];
                af[i] *= sh;
            }
#pragma unroll
            for (int j = 0; j < 8; j++) bf[j] = *(const half8*)&Bs[1][boff[j]];
#pragma unroll
            for (int i = 0; i < 4; i++)
#pragma unroll
                for (int j = 0; j < 8; j++)
                    acc[i][j] = __builtin_amdgcn_mfma_f32_16x16x32_f16(af[i], bf[j], acc[i][j], 0, 0, 0);
        }
        __syncthreads();
    }

    half_t* o = O16 + (long)z * SEQ * HID;
#pragma unroll
    for (int i = 0; i < 4; i++) {
        long mrow = m0 + wm * 64 + i * 16 + quad * 4;
        int rl = wm * 64 + i * 16 + quad * 4;
#pragma unroll
        for (int j = 0; j < 8; j++) {
            long gn = h0 + wn * 128 + j * 16 + lanen;
#pragma unroll
            for (int r = 0; r < 4; r++)
                o[(mrow + r) * HID + gn] = (half_t)(acc[i][j][r] * invS[rl + r]);
        }
    }
}

// ---------------- host ----------------
extern "C" void kernel_launch(void* const* d_in, const int* in_sizes, int n_in,
                              void* d_out, int out_size, void* d_ws, size_t ws_size,
                              hipStream_t stream) {
    const float* h  = (const float*)d_in[0];
    const float* Wv = (const float*)d_in[1];
    const float* bv = (const float*)d_in[2];
    const float* Wk = (const float*)d_in[3];
    const float* bk = (const float*)d_in[4];
    const float* Wq = (const float*)d_in[5];
    const float* bq = (const float*)d_in[6];
    const float* Wo = (const float*)d_in[7];
    const float* bo = (const float*)d_in[8];

    uint8_t* ws = (uint8_t*)d_ws;
    size_t off = 0;
    auto alloc = [&](size_t bytes) { size_t o = off; off += (bytes + 255) & ~(size_t)255; return o; };

    half_t* W16   = (half_t*)(ws + alloc((size_t)3 * HID * DIN * 2)); // [Wv][Wk][Wq]
    half_t* Wo16  = (half_t*)(ws + alloc((size_t)DIN * HID * 2));
    float*  biasq = (float*)(ws + alloc((size_t)3 * HID * 4));        // [bv][bk][bq]
    half_t* k16   = (half_t*)(ws + alloc((size_t)MTOT * HID * 2));
    half_t* q16   = (half_t*)(ws + alloc((size_t)MTOT * HID * 2));    // reused as O16 per group
    half_t* vT    = (half_t*)(ws + alloc((size_t)MTOT * HID * 2));    // [b][h][m]
    size_t h16_off = alloc((size_t)MTOT * DIN * 2);
    half_t* h16   = (half_t*)(ws + h16_off);
    half_t* O16 = q16;  // q dead after its group's se_k; O written strictly after

    // E + stats overlap the (dead-after-K1) h16 region onward
    size_t s_avail = ws_size > h16_off ? ws_size - h16_off : 0;
    size_t per_batch = (size_t)SEQ * SEQ * 2 + 2 * 8 * SEQ * 4;
    int GB = (int)(s_avail / per_batch);
    if (GB < 1)  GB = 1;
    if (GB > NB) GB = NB;
    half_t* Ebuf  = (half_t*)(ws + h16_off);
    float*  Mstat = (float*)(ws + h16_off + (size_t)GB * SEQ * SEQ * 2);
    float*  Lstat = Mstat + (size_t)GB * 8 * SEQ;

    // K0: conversions
    cvt_kernel<<<dim3((MTOT * DIN / 4 + 255) / 256), 256, 0, stream>>>(h, h16, MTOT * DIN / 4);
    cvt4_kernel<<<dim3((HID * DIN / 4 + 255) / 256, 4), 256, 0, stream>>>(
        Wv, Wk, Wq, Wo, W16, W16 + HID * DIN, W16 + 2 * HID * DIN, Wo16, HID * DIN / 4);
    pack_bias<<<dim3(1), 512, 0, stream>>>(bv, bk, bq, biasq);

    // K1: QKV projections (z: 0=V->vT, 1=K, 2=Q)
    gemm_k<0><<<dim3(MTOT / 128, HID / 128, 3), 256, 0, stream>>>(
        h16, DIN, 0,
        W16, DIN, (long)HID * DIN,
        (void*)k16, HID, (long)MTOT * HID,
        biasq, DIN, vT);

    for (int g0 = 0; g0 < NB; g0 += GB) {
        int gb = NB - g0 < GB ? NB - g0 : GB;
        // K2: E = exp(q k^T - m_loc) + stats  (128x256 tiles)
        se_k<<<dim3(SEQ / 128, SEQ / 256, gb), 256, 0, stream>>>(
            q16 + (size_t)g0 * SEQ * HID,
            k16 + (size_t)g0 * SEQ * HID,
            Ebuf, Mstat, Lstat);
        // K4: O = (scaled E) vT / lsum  (128x256 tiles)
        pv_k<<<dim3(SEQ / 128, HID / 256, gb), 256, 0, stream>>>(
            Ebuf, vT + (size_t)g0 * HID * SEQ,
            Mstat, Lstat,
            O16 + (size_t)g0 * SEQ * HID);
    }

    // K5: out = relu(O Wo^T + bo)  (f32 out)
    gemm_k<3><<<dim3(MTOT / 128, DIN / 128, 1), 256, 0, stream>>>(
        O16, HID, 0,
        Wo16, HID, 0,
        d_out, DIN, 0,
        bo, HID, nullptr);

    (void)in_sizes; (void)n_in; (void)out_size;
}

// Round 7
// 262.177 us; speedup vs baseline: 2.1664x; 1.0670x over previous
//
#include <hip/hip_runtime.h>
#include <cstdint>
#include <cstddef>

#define NB    32          // batches
#define SEQ   1024        // sequence length
#define DIN   256
#define HID   512
#define MTOT  32768       // NB*SEQ

typedef _Float16 half_t;
typedef _Float16 half8  __attribute__((ext_vector_type(8)));
typedef _Float16 half4v __attribute__((ext_vector_type(4)));
typedef float    f32x4  __attribute__((ext_vector_type(4)));

typedef __attribute__((address_space(1))) const void* gas_ptr;
typedef __attribute__((address_space(3))) void*       las_ptr;

// ---------------- f32 -> f16 convert ----------------
__global__ void cvt_kernel(const float* __restrict__ src, half_t* __restrict__ dst, int n4) {
    int i = blockIdx.x * blockDim.x + threadIdx.x;
    if (i < n4) {
        f32x4 v = ((const f32x4*)src)[i];
        half4v h;
        h[0] = (half_t)v[0]; h[1] = (half_t)v[1]; h[2] = (half_t)v[2]; h[3] = (half_t)v[3];
        ((half4v*)dst)[i] = h;
    }
}

// all 4 weight matrices are HID*DIN == DIN*HID elements; blockIdx.y selects
__global__ void cvt4_kernel(const float* __restrict__ s0, const float* __restrict__ s1,
                            const float* __restrict__ s2, const float* __restrict__ s3,
                            half_t* __restrict__ d0, half_t* __restrict__ d1,
                            half_t* __restrict__ d2, half_t* __restrict__ d3, int n4) {
    int y = blockIdx.y;
    const float* s = y == 0 ? s0 : y == 1 ? s1 : y == 2 ? s2 : s3;
    half_t*      d = y == 0 ? d0 : y == 1 ? d1 : y == 2 ? d2 : d3;
    int i = blockIdx.x * blockDim.x + threadIdx.x;
    if (i < n4) {
        f32x4 v = ((const f32x4*)s)[i];
        half4v h;
        h[0] = (half_t)v[0]; h[1] = (half_t)v[1]; h[2] = (half_t)v[2]; h[3] = (half_t)v[3];
        ((half4v*)d)[i] = h;
    }
}

__global__ void pack_bias(const float* __restrict__ bv, const float* __restrict__ bk,
                          const float* __restrict__ bq, float* __restrict__ dst) {
    int t = threadIdx.x;
    if (t < HID) {
        dst[t]         = bv[t];
        dst[HID + t]   = bk[t];
        dst[2*HID + t] = bq[t];
    }
}

// ---------------- generic GEMM (projections), 128x128 tile ----------------
// C[m][n] = sum_k A[m][k] * B[n][k]
// K-loop unrolled x2: two 32-wide sub-buffers, one sync pair per 64-wide step.
// MODE 0: QKV proj. bias+relu, f16 out. z=0 -> transposed into out2 (vT[b][h][m]); z=1,2 -> row-major.
// MODE 3: out proj. f32 out, bias+relu.
template<int MODE>
__global__ __launch_bounds__(256, 2) void gemm_k(
    const half_t* __restrict__ A, long lda, long a_bs,
    const half_t* __restrict__ Bw, long ldb, long b_bs,
    void* __restrict__ Out, long ldo, long o_bs,
    const float* __restrict__ bias,
    int Kdim, half_t* __restrict__ out2)
{
    __shared__ alignas(16) half_t As[2][128 * 32];
    __shared__ alignas(16) half_t Bs[2][128 * 32];

    const int t    = threadIdx.x;
    const int lane = t & 63;
    const int wave = t >> 6;
    const int wm   = wave >> 1;
    const int wn   = wave & 1;
    const int lanen = lane & 15;
    const int quad  = lane >> 4;
    const int z     = blockIdx.z;
    const long m0 = (long)blockIdx.x * 128;
    const long n0 = (long)blockIdx.y * 128;

    const half_t* Ab = A  + (long)z * a_bs;
    const half_t* Bb = Bw + (long)z * b_bs;

    f32x4 acc[4][4];
#pragma unroll
    for (int i = 0; i < 4; i++)
#pragma unroll
        for (int j = 0; j < 4; j++)
            acc[i][j] = f32x4{0.f, 0.f, 0.f, 0.f};

    const int c0 = t, c1 = t + 256;
    const int r0 = c0 >> 2, kc0 = c0 & 3;
    const int r1 = c1 >> 2, kc1 = c1 & 3;

    const half_t* gA0 = Ab + (m0 + r0) * lda + kc0 * 8;
    const half_t* gA1 = Ab + (m0 + r1) * lda + kc1 * 8;
    const half_t* gB0 = Bb + (n0 + r0) * ldb + kc0 * 8;
    const half_t* gB1 = Bb + (n0 + r1) * ldb + kc1 * 8;
    const int lA0 = c0 * 8, lA1 = c1 * 8;
    const int lB0 = c0 * 8, lB1 = c1 * 8;

    int aoff[4], boff[4];
#pragma unroll
    for (int i = 0; i < 4; i++) aoff[i] = (wm * 64 + i * 16 + lanen) * 32 + quad * 8;
#pragma unroll
    for (int j = 0; j < 4; j++) boff[j] = (wn * 64 + j * 16 + lanen) * 32 + quad * 8;

    for (int k0 = 0; k0 < Kdim; k0 += 64) {
#pragma unroll
        for (int sub = 0; sub < 2; sub++) {
            const int ks = k0 + sub * 32;
            __builtin_amdgcn_global_load_lds((gas_ptr)(gA0 + ks), (las_ptr)&As[sub][lA0], 16, 0, 0);
            __builtin_amdgcn_global_load_lds((gas_ptr)(gA1 + ks), (las_ptr)&As[sub][lA1], 16, 0, 0);
            __builtin_amdgcn_global_load_lds((gas_ptr)(gB0 + ks), (las_ptr)&Bs[sub][lB0], 16, 0, 0);
            __builtin_amdgcn_global_load_lds((gas_ptr)(gB1 + ks), (las_ptr)&Bs[sub][lB1], 16, 0, 0);
        }
        __syncthreads();

        {
            half8 af[4], bf[4];
#pragma unroll
            for (int i = 0; i < 4; i++) af[i] = *(const half8*)&As[0][aoff[i]];
#pragma unroll
            for (int j = 0; j < 4; j++) bf[j] = *(const half8*)&Bs[0][boff[j]];
#pragma unroll
            for (int i = 0; i < 4; i++)
#pragma unroll
                for (int j = 0; j < 4; j++)
                    acc[i][j] = __builtin_amdgcn_mfma_f32_16x16x32_f16(af[i], bf[j], acc[i][j], 0, 0, 0);
        }
        {
            half8 af[4], bf[4];
#pragma unroll
            for (int i = 0; i < 4; i++) af[i] = *(const half8*)&As[1][aoff[i]];
#pragma unroll
            for (int j = 0; j < 4; j++) bf[j] = *(const half8*)&Bs[1][boff[j]];
#pragma unroll
            for (int i = 0; i < 4; i++)
#pragma unroll
                for (int j = 0; j < 4; j++)
                    acc[i][j] = __builtin_amdgcn_mfma_f32_16x16x32_f16(af[i], bf[j], acc[i][j], 0, 0, 0);
        }
        __syncthreads();
    }

    // C/D layout: col = lane&15, row = quad*4 + reg
#pragma unroll
    for (int i = 0; i < 4; i++) {
        long mrow = m0 + wm * 64 + i * 16 + quad * 4;
#pragma unroll
        for (int j = 0; j < 4; j++) {
            long gn = n0 + wn * 64 + j * 16 + lanen;
            f32x4 v = acc[i][j];
            if (MODE == 0) {
                float bb = bias[z * HID + gn];
                half_t h0 = (half_t)fmaxf(v[0] + bb, 0.f);
                half_t h1 = (half_t)fmaxf(v[1] + bb, 0.f);
                half_t h2 = (half_t)fmaxf(v[2] + bb, 0.f);
                half_t h3 = (half_t)fmaxf(v[3] + bb, 0.f);
                if (z == 0) {
                    long bidx = mrow >> 10;
                    long pos  = mrow & 1023;
                    half4v pk; pk[0] = h0; pk[1] = h1; pk[2] = h2; pk[3] = h3;
                    *(half4v*)(out2 + ((bidx * HID + gn) << 10) + pos) = pk;
                } else {
                    half_t* o = (half_t*)Out + (long)(z - 1) * o_bs;
                    o[(mrow + 0) * ldo + gn] = h0;
                    o[(mrow + 1) * ldo + gn] = h1;
                    o[(mrow + 2) * ldo + gn] = h2;
                    o[(mrow + 3) * ldo + gn] = h3;
                }
            } else {
                float* o = (float*)Out;
                float bb = bias[gn];
#pragma unroll
                for (int r = 0; r < 4; r++) o[(mrow + r) * ldo + gn] = fmaxf(v[r] + bb, 0.f);
            }
        }
    }
}

// ---------------- S = q k^T with fused exp, 128x256 tile ----------------
// SWZ=1: 1-D grid, wgid = xcd + 8*(tile + 32*zq) -> batch z = xcd + 8*zq pinned to
// XCD (hw: linear%8). All of batch z's Q/K re-reads become L2 hits (2 MB << 4 MB L2).
// Each wave-column (wn) spans exactly one 128-col stats block -> per-wave stats.
template<int SWZ>
__global__ __launch_bounds__(256, 2) void se_k(
    const half_t* __restrict__ Q, const half_t* __restrict__ K,
    half_t* __restrict__ E, float* __restrict__ Mstat, float* __restrict__ Lstat)
{
    __shared__ alignas(16) half_t As[2][128 * 32];
    __shared__ alignas(16) half_t Bs[2][256 * 32];

    const int t    = threadIdx.x;
    const int lane = t & 63;
    const int wave = t >> 6;
    const int wm   = wave >> 1;
    const int wn   = wave & 1;
    const int lanen = lane & 15;
    const int quad  = lane >> 4;

    int bx, by, z;
    if (SWZ) {
        const int wgid = blockIdx.x;
        const int c    = wgid & 7;        // XCD
        const int tmp  = wgid >> 3;
        const int tile = tmp & 31;        // 32 tiles (8m x 4n) per batch
        z  = c + 8 * (tmp >> 5);
        bx = tile & 7;
        by = tile >> 3;
    } else {
        bx = blockIdx.x; by = blockIdx.y; z = blockIdx.z;
    }
    const long m0 = (long)bx * 128;
    const long n0 = (long)by * 256;

    const half_t* Ab = Q + (long)z * SEQ * HID;
    const half_t* Bb = K + (long)z * SEQ * HID;

    f32x4 acc[4][8];
#pragma unroll
    for (int i = 0; i < 4; i++)
#pragma unroll
        for (int j = 0; j < 8; j++)
            acc[i][j] = f32x4{0.f, 0.f, 0.f, 0.f};

    // A: 512 chunks (2/thread), B: 1024 chunks (4/thread); chunk c -> row c>>2, kchunk c&3
    const half_t* gA[2]; int lA[2];
    const half_t* gB[4]; int lB[4];
#pragma unroll
    for (int s = 0; s < 2; s++) {
        int c = t + 256 * s;
        gA[s] = Ab + (m0 + (c >> 2)) * HID + (c & 3) * 8;
        lA[s] = c * 8;
    }
#pragma unroll
    for (int s = 0; s < 4; s++) {
        int c = t + 256 * s;
        gB[s] = Bb + (n0 + (c >> 2)) * HID + (c & 3) * 8;
        lB[s] = c * 8;
    }

    int aoff[4], boff[8];
#pragma unroll
    for (int i = 0; i < 4; i++) aoff[i] = (wm * 64 + i * 16 + lanen) * 32 + quad * 8;
#pragma unroll
    for (int j = 0; j < 8; j++) boff[j] = (wn * 128 + j * 16 + lanen) * 32 + quad * 8;

    for (int k0 = 0; k0 < HID; k0 += 64) {
#pragma unroll
        for (int sub = 0; sub < 2; sub++) {
            const int ks = k0 + sub * 32;
#pragma unroll
            for (int s = 0; s < 2; s++)
                __builtin_amdgcn_global_load_lds((gas_ptr)(gA[s] + ks), (las_ptr)&As[sub][lA[s]], 16, 0, 0);
#pragma unroll
            for (int s = 0; s < 4; s++)
                __builtin_amdgcn_global_load_lds((gas_ptr)(gB[s] + ks), (las_ptr)&Bs[sub][lB[s]], 16, 0, 0);
        }
        __syncthreads();

        {
            half8 af[4], bf[8];
#pragma unroll
            for (int i = 0; i < 4; i++) af[i] = *(const half8*)&As[0][aoff[i]];
#pragma unroll
            for (int j = 0; j < 8; j++) bf[j] = *(const half8*)&Bs[0][boff[j]];
#pragma unroll
            for (int i = 0; i < 4; i++)
#pragma unroll
                for (int j = 0; j < 8; j++)
                    acc[i][j] = __builtin_amdgcn_mfma_f32_16x16x32_f16(af[i], bf[j], acc[i][j], 0, 0, 0);
        }
        {
            half8 af[4], bf[8];
#pragma unroll
            for (int i = 0; i < 4; i++) af[i] = *(const half8*)&As[1][aoff[i]];
#pragma unroll
            for (int j = 0; j < 8; j++) bf[j] = *(const half8*)&Bs[1][boff[j]];
#pragma unroll
            for (int i = 0; i < 4; i++)
#pragma unroll
                for (int j = 0; j < 8; j++)
                    acc[i][j] = __builtin_amdgcn_mfma_f32_16x16x32_f16(af[i], bf[j], acc[i][j], 0, 0, 0);
        }
        __syncthreads();
    }

    // ---- epilogue: per-wave row max over this wave's 128 cols ----
    float mf[4][4];
#pragma unroll
    for (int i = 0; i < 4; i++)
#pragma unroll
        for (int r = 0; r < 4; r++) {
            float v = acc[i][0][r];
#pragma unroll
            for (int j = 1; j < 8; j++) v = fmaxf(v, acc[i][j][r]);
#pragma unroll
            for (int off = 8; off > 0; off >>= 1)
                v = fmaxf(v, __shfl_xor(v, off, 64));
            mf[i][r] = v;
        }

    // ---- exp + row partial sums + E store ----
    half_t* Eb = E + (long)z * SEQ * SEQ;
    float rs[4][4];
#pragma unroll
    for (int i = 0; i < 4; i++)
#pragma unroll
        for (int r = 0; r < 4; r++) rs[i][r] = 0.f;
#pragma unroll
    for (int i = 0; i < 4; i++) {
        long mrow = m0 + wm * 64 + i * 16 + quad * 4;
#pragma unroll
        for (int j = 0; j < 8; j++) {
            long gn = n0 + wn * 128 + j * 16 + lanen;
#pragma unroll
            for (int r = 0; r < 4; r++) {
                float e = __expf(acc[i][j][r] - mf[i][r]);
                rs[i][r] += e;
                Eb[(mrow + r) * SEQ + gn] = (half_t)e;
            }
        }
    }
#pragma unroll
    for (int i = 0; i < 4; i++)
#pragma unroll
        for (int r = 0; r < 4; r++) {
            float v = rs[i][r];
#pragma unroll
            for (int off = 8; off > 0; off >>= 1)
                v += __shfl_xor(v, off, 64);
            rs[i][r] = v;
        }

    // stats: kb = by*2 + wn; rows are wave-private -> no conflicts
    if (lanen == 0) {
        long base = ((long)z * 8 + by * 2 + wn) * SEQ + m0 + wm * 64;
#pragma unroll
        for (int i = 0; i < 4; i++)
#pragma unroll
            for (int r = 0; r < 4; r++) {
                Mstat[base + i * 16 + quad * 4 + r] = mf[i][r];
                Lstat[base + i * 16 + quad * 4 + r] = rs[i][r];
            }
    }
}

// ---------------- O = P vT with stat-merge rescale + normalize, 128x256 tile ----------------
// SWZ=1: 1-D grid, wgid = xcd + 8*(tile + 16*zq) -> batch pinned to XCD (E+vT L2-resident).
template<int SWZ>
__global__ __launch_bounds__(256, 2) void pv_k(
    const half_t* __restrict__ E, const half_t* __restrict__ vT,
    const float* __restrict__ Mstat, const float* __restrict__ Lstat,
    half_t* __restrict__ O16)
{
    __shared__ alignas(16) half_t As[2][128 * 32];
    __shared__ alignas(16) half_t Bs[2][256 * 32];
    __shared__ float scaleS[8][128];
    __shared__ float invS[128];

    const int t    = threadIdx.x;
    const int lane = t & 63;
    const int wave = t >> 6;
    const int wm   = wave >> 1;
    const int wn   = wave & 1;
    const int lanen = lane & 15;
    const int quad  = lane >> 4;

    int bx, by, z;
    if (SWZ) {
        const int wgid = blockIdx.x;
        const int c    = wgid & 7;        // XCD
        const int tmp  = wgid >> 3;
        const int tile = tmp & 15;        // 16 tiles (8m x 2h) per batch
        z  = c + 8 * (tmp >> 4);
        bx = tile & 7;
        by = tile >> 3;
    } else {
        bx = blockIdx.x; by = blockIdx.y; z = blockIdx.z;
    }
    const long m0 = (long)bx * 128;
    const long h0 = (long)by * 256;

    // prologue: merge per-col-block stats for this block's 128 rows
    if (t < 128) {
        float mv[8];
        float M = -1e30f;
#pragma unroll
        for (int kb = 0; kb < 8; kb++) {
            mv[kb] = Mstat[((long)z * 8 + kb) * SEQ + m0 + t];
            M = fmaxf(M, mv[kb]);
        }
        float ls = 0.f;
#pragma unroll
        for (int kb = 0; kb < 8; kb++) {
            float sc = __expf(mv[kb] - M);
            scaleS[kb][t] = sc;
            ls += Lstat[((long)z * 8 + kb) * SEQ + m0 + t] * sc;
        }
        invS[t] = 1.f / ls;
    }
    __syncthreads();

    const half_t* Ab = E  + (long)z * SEQ * SEQ;
    const half_t* Bb = vT + (long)z * HID * SEQ;

    f32x4 acc[4][8];
#pragma unroll
    for (int i = 0; i < 4; i++)
#pragma unroll
        for (int j = 0; j < 8; j++)
            acc[i][j] = f32x4{0.f, 0.f, 0.f, 0.f};

    const half_t* gA[2]; int lA[2];
    const half_t* gB[4]; int lB[4];
#pragma unroll
    for (int s = 0; s < 2; s++) {
        int c = t + 256 * s;
        gA[s] = Ab + (m0 + (c >> 2)) * SEQ + (c & 3) * 8;
        lA[s] = c * 8;
    }
#pragma unroll
    for (int s = 0; s < 4; s++) {
        int c = t + 256 * s;
        gB[s] = Bb + (h0 + (c >> 2)) * SEQ + (c & 3) * 8;
        lB[s] = c * 8;
    }

    int aoff[4], boff[8];
#pragma unroll
    for (int i = 0; i < 4; i++) aoff[i] = (wm * 64 + i * 16 + lanen) * 32 + quad * 8;
#pragma unroll
    for (int j = 0; j < 8; j++) boff[j] = (wn * 128 + j * 16 + lanen) * 32 + quad * 8;

    for (int k0 = 0; k0 < SEQ; k0 += 64) {
#pragma unroll
        for (int sub = 0; sub < 2; sub++) {
            const int ks = k0 + sub * 32;
#pragma unroll
            for (int s = 0; s < 2; s++)
                __builtin_amdgcn_global_load_lds((gas_ptr)(gA[s] + ks), (las_ptr)&As[sub][lA[s]], 16, 0, 0);
#pragma unroll
            for (int s = 0; s < 4; s++)
                __builtin_amdgcn_global_load_lds((gas_ptr)(gB[s] + ks), (las_ptr)&Bs[sub][lB[s]], 16, 0, 0);
        }
        __syncthreads();

        const int kb = k0 >> 7;   // both 32-wide subs lie in the same 128-col stats block
        {
            half8 af[4], bf[8];
#pragma unroll
            for (int i = 0; i < 4; i++) {
                af[i] = *(const half8*)&As[0][aoff[i]];
                half_t sh = (half_t)scaleS[kb][wm * 64 + i * 16 + lanen];
                af[i] *= sh;   // per-row rescale exp(m_kb - M); A-operand row = lane&15
            }
#pragma unroll
            for (int j = 0; j < 8; j++) bf[j] = *(const half8*)&Bs[0][boff[j]];
#pragma unroll
            for (int i = 0; i < 4; i++)
#pragma unroll
                for (int j = 0; j < 8; j++)
                    acc[i][j] = __builtin_amdgcn_mfma_f32_16x16x32_f16(af[i], bf[j], acc[i][j], 0, 0, 0);
        }
        {
            half8 af[4], bf[8];
#pragma unroll
            for (int i = 0; i < 4; i++) {
                af[i] = *(const half8*)&As[1][aoff[i]];
                half_t sh = (half_t)scaleS[kb][wm * 64 + i * 16 + lanen];
                af[i] *= sh;
            }
#pragma unroll
            for (int j = 0; j < 8; j++) bf[j] = *(const half8*)&Bs[1][boff[j]];
#pragma unroll
            for (int i = 0; i < 4; i++)
#pragma unroll
                for (int j = 0; j < 8; j++)
                    acc[i][j] = __builtin_amdgcn_mfma_f32_16x16x32_f16(af[i], bf[j], acc[i][j], 0, 0, 0);
        }
        __syncthreads();
    }

    half_t* o = O16 + (long)z * SEQ * HID;
#pragma unroll
    for (int i = 0; i < 4; i++) {
        long mrow = m0 + wm * 64 + i * 16 + quad * 4;
        int rl = wm * 64 + i * 16 + quad * 4;
#pragma unroll
        for (int j = 0; j < 8; j++) {
            long gn = h0 + wn * 128 + j * 16 + lanen;
#pragma unroll
            for (int r = 0; r < 4; r++)
                o[(mrow + r) * HID + gn] = (half_t)(acc[i][j][r] * invS[rl + r]);
        }
    }
}

// ---------------- host ----------------
extern "C" void kernel_launch(void* const* d_in, const int* in_sizes, int n_in,
                              void* d_out, int out_size, void* d_ws, size_t ws_size,
                              hipStream_t stream) {
    const float* h  = (const float*)d_in[0];
    const float* Wv = (const float*)d_in[1];
    const float* bv = (const float*)d_in[2];
    const float* Wk = (const float*)d_in[3];
    const float* bk = (const float*)d_in[4];
    const float* Wq = (const float*)d_in[5];
    const float* bq = (const float*)d_in[6];
    const float* Wo = (const float*)d_in[7];
    const float* bo = (const float*)d_in[8];

    uint8_t* ws = (uint8_t*)d_ws;
    size_t off = 0;
    auto alloc = [&](size_t bytes) { size_t o = off; off += (bytes + 255) & ~(size_t)255; return o; };

    half_t* W16   = (half_t*)(ws + alloc((size_t)3 * HID * DIN * 2)); // [Wv][Wk][Wq]
    half_t* Wo16  = (half_t*)(ws + alloc((size_t)DIN * HID * 2));
    float*  biasq = (float*)(ws + alloc((size_t)3 * HID * 4));        // [bv][bk][bq]
    half_t* k16   = (half_t*)(ws + alloc((size_t)MTOT * HID * 2));
    half_t* q16   = (half_t*)(ws + alloc((size_t)MTOT * HID * 2));    // reused as O16 per group
    half_t* vT    = (half_t*)(ws + alloc((size_t)MTOT * HID * 2));    // [b][h][m]
    size_t h16_off = alloc((size_t)MTOT * DIN * 2);
    half_t* h16   = (half_t*)(ws + h16_off);
    half_t* O16 = q16;  // q dead after its group's se_k; O written strictly after

    // E + stats overlap the (dead-after-K1) h16 region onward
    size_t s_avail = ws_size > h16_off ? ws_size - h16_off : 0;
    size_t per_batch = (size_t)SEQ * SEQ * 2 + 2 * 8 * SEQ * 4;
    int GB = (int)(s_avail / per_batch);
    if (GB < 1)  GB = 1;
    if (GB > NB) GB = NB;
    half_t* Ebuf  = (half_t*)(ws + h16_off);
    float*  Mstat = (float*)(ws + h16_off + (size_t)GB * SEQ * SEQ * 2);
    float*  Lstat = Mstat + (size_t)GB * 8 * SEQ;

    // K0: conversions
    cvt_kernel<<<dim3((MTOT * DIN / 4 + 255) / 256), 256, 0, stream>>>(h, h16, MTOT * DIN / 4);
    cvt4_kernel<<<dim3((HID * DIN / 4 + 255) / 256, 4), 256, 0, stream>>>(
        Wv, Wk, Wq, Wo, W16, W16 + HID * DIN, W16 + 2 * HID * DIN, Wo16, HID * DIN / 4);
    pack_bias<<<dim3(1), 512, 0, stream>>>(bv, bk, bq, biasq);

    // K1: QKV projections (z: 0=V->vT, 1=K, 2=Q)
    gemm_k<0><<<dim3(MTOT / 128, HID / 128, 3), 256, 0, stream>>>(
        h16, DIN, 0,
        W16, DIN, (long)HID * DIN,
        (void*)k16, HID, (long)MTOT * HID,
        biasq, DIN, vT);

    if (GB == NB) {
        // XCD-pinned path: each batch's tiles land on XCD z%8 -> Q/K (se) and E/vT (pv)
        // are L2-resident per batch; staging re-reads become L2 hits.
        se_k<1><<<dim3(NB * 32), 256, 0, stream>>>(q16, k16, Ebuf, Mstat, Lstat);
        pv_k<1><<<dim3(NB * 16), 256, 0, stream>>>(Ebuf, vT, Mstat, Lstat, O16);
    } else {
        for (int g0 = 0; g0 < NB; g0 += GB) {
            int gb = NB - g0 < GB ? NB - g0 : GB;
            se_k<0><<<dim3(SEQ / 128, SEQ / 256, gb), 256, 0, stream>>>(
                q16 + (size_t)g0 * SEQ * HID,
                k16 + (size_t)g0 * SEQ * HID,
                Ebuf, Mstat, Lstat);
            pv_k<0><<<dim3(SEQ / 128, HID / 256, gb), 256, 0, stream>>>(
                Ebuf, vT + (size_t)g0 * HID * SEQ,
                Mstat, Lstat,
                O16 + (size_t)g0 * SEQ * HID);
        }
    }

    // K5: out = relu(O Wo^T + bo)  (f32 out)
    gemm_k<3><<<dim3(MTOT / 128, DIN / 128, 1), 256, 0, stream>>>(
        O16, HID, 0,
        Wo16, HID, 0,
        d_out, DIN, 0,
        bo, HID, nullptr);

    (void)in_sizes; (void)n_in; (void)out_size;
}